// Round 1
// 1685.707 us; speedup vs baseline: 1.0122x; 1.0122x over previous
//
#include <hip/hip_runtime.h>
#include <hip/hip_bf16.h>

#define NN 50000
#define EE 800000
#define HH 128

typedef __attribute__((ext_vector_type(8))) short bf16x8;
typedef __attribute__((ext_vector_type(4))) float f32x4;

__device__ inline unsigned short f2bf(float f) {
    union { float f; unsigned u; } v; v.f = f;
    unsigned r = v.u + 0x7FFF + ((v.u >> 16) & 1);
    return (unsigned short)(r >> 16);
}

// ---------------- CSR build (edges grouped by dst) ----------------
__global__ __launch_bounds__(256) void hist_k(const int* __restrict__ dst, int* __restrict__ cnt) {
    int i = blockIdx.x * 256 + threadIdx.x;
    if (i < EE) atomicAdd(&cnt[dst[i]], 1);
}

__global__ __launch_bounds__(256) void blocksum_k(const int* __restrict__ cnt, int* __restrict__ bsum) {
    __shared__ int sm[256];
    int i = blockIdx.x * 256 + threadIdx.x;
    sm[threadIdx.x] = (i < NN) ? cnt[i] : 0;
    __syncthreads();
    for (int s = 128; s > 0; s >>= 1) {
        if (threadIdx.x < s) sm[threadIdx.x] += sm[threadIdx.x + s];
        __syncthreads();
    }
    if (threadIdx.x == 0) bsum[blockIdx.x] = sm[0];
}

__global__ __launch_bounds__(256) void scanb_k(int* __restrict__ bsum, int nb) {
    __shared__ int sm[256];
    int t = threadIdx.x;
    sm[t] = (t < nb) ? bsum[t] : 0;
    __syncthreads();
    for (int d = 1; d < 256; d <<= 1) {
        int v = (t >= d) ? sm[t - d] : 0;
        __syncthreads();
        sm[t] += v;
        __syncthreads();
    }
    if (t < nb) bsum[t] = sm[t];
}

__global__ __launch_bounds__(256) void offsets_k(const int* __restrict__ cnt, const int* __restrict__ bsum,
                                                 int* __restrict__ offsets, int* __restrict__ cursor) {
    __shared__ int sm[256];
    int b = blockIdx.x, t = threadIdx.x;
    int i = b * 256 + t;
    int c = (i < NN) ? cnt[i] : 0;
    sm[t] = c;
    __syncthreads();
    for (int d = 1; d < 256; d <<= 1) {
        int v = (t >= d) ? sm[t - d] : 0;
        __syncthreads();
        sm[t] += v;
        __syncthreads();
    }
    int incl = sm[t];
    int base = (b == 0) ? 0 : bsum[b - 1];
    int off = base + incl - c;
    if (i < NN) { offsets[i] = off; cursor[i] = off; }
    if (i == NN - 1) offsets[NN] = off + c;
}

__global__ __launch_bounds__(256) void fill_k(const int* __restrict__ dst, int* __restrict__ cursor,
                                              int* __restrict__ eids) {
    int i = blockIdx.x * 256 + threadIdx.x;
    if (i < EE) { int p = atomicAdd(&cursor[dst[i]], 1); eids[p] = i; }
}

// ---------------- weight prep: W[fi][fo] f32 -> W''[n][k] bf16, chunk-swizzled ----------------
// W''_swz[n][kb*32 + c*8 + j] = W[kb*32 + (c^(n&3))*8 + j][n]
// so a LINEAR global_load_lds into LDS[n][c] lands orig chunk (c^(n&3)); reader XORs.
__global__ __launch_bounds__(256) void wprep_k(const float* __restrict__ W, unsigned short* __restrict__ out,
                                               int fi, int fo, int n_off, int out_ld) {
    int i = blockIdx.x * 256 + threadIdx.x;
    if (i >= fi * fo) return;
    int n = i / fi, kout = i - n * fi;
    int c = (kout >> 3) & 3;
    int ksrc = (kout & ~31) | (((c ^ (n & 3)) & 3) << 3) | (kout & 7);
    out[(size_t)(n_off + n) * out_ld + kout] = f2bf(W[(size_t)ksrc * fo + n]);
}

// ---------------- MFMA gather-GEMM ----------------
// C[M, 128*NCW per block] = act( concat_g Ag[idx_g(row)] @ W + bias )
// NCW=1: 128x128 tile, 4 waves. NCW=2: 128x256 tile, 8 waves (waves 0-3 col-half 0,
// waves 4-7 col-half 1; A stream shared -> HBM fetch of A halves vs two col-tile grid).
// Each wave: 32 rows, M_rep=2 x N_rep=8 of 16x16x32 bf16 MFMA, BK=32.
// A: direct global loads (f32->bf16 inline, or bf16 passthrough per bfmask bit),
//    software-pipelined one k-step ahead (issue st+1 loads before the st barrier so
//    the barrier's vmcnt drain absorbs the gather latency).
// W: bf16 [NCtot][Ktot] pre-swizzled; staged to LDS via global_load_lds, double-buffered.
// mode: 0 f32, 1 f32+relu, 2 bf16, 4 bf16+relu, 3 relu+resid+LayerNorm(128) f32.
template <int NCW>
__global__ __launch_bounds__(NCW * 256) void mm_k(
    const void* __restrict__ A0, const int* __restrict__ idx0,
    const void* __restrict__ A1, const int* __restrict__ idx1,
    const void* __restrict__ A2, const int* __restrict__ idx2,
    int bfmask,
    const unsigned short* __restrict__ Wsz, const float* __restrict__ bias,
    int M, int Ktot, int mode,
    float* __restrict__ Cf, unsigned short* __restrict__ Cb, int out_ld,
    const float* __restrict__ resid, const float* __restrict__ gamma, const float* __restrict__ beta)
{
    __shared__ unsigned short Bs[2][NCW * 4096]; // 2 x (NCW*8KB): [n(128*NCW)][k(32)] bf16, chunk-swizzled
    const int t = threadIdx.x;
    const int wid = t >> 6, lane = t & 63;
    const int mwid = wid & 3;     // row-wave 0..3
    const int colw = wid >> 2;    // col-half 0..NCW-1
    const int lr = lane & 15, lk = lane >> 4;
    const int ncb = (blockIdx.y * NCW) << 7;   // first output col of this block
    const int col0 = ncb + (colw << 7);        // first output col of this wave
    const int wrow = (blockIdx.x << 7) + mwid * 32;

    int r0 = wrow + lr;      if (r0 >= M) r0 = M - 1;
    int r1 = wrow + 16 + lr; if (r1 >= M) r1 = M - 1;

    const int nt = Ktot >> 5;

    f32x4 acc[2][8];
    #pragma unroll
    for (int i = 0; i < 2; ++i)
        #pragma unroll
        for (int j = 0; j < 8; ++j) acc[i][j] = (f32x4){0.f, 0.f, 0.f, 0.f};

    // stage B k-block st into buffer buf (all waves cover 128*NCW n-rows x 64B)
    auto stageB = [&](int st, int buf) {
        #pragma unroll
        for (int i = 0; i < 2; ++i) {
            int s = wid * 128 + i * 64 + lane;                   // [0, NCW*512)
            const unsigned short* src = Wsz + (size_t)(ncb + (s >> 2)) * Ktot + (st << 5) + ((s & 3) << 3);
            unsigned short* dst = &Bs[buf][wid * 1024 + i * 512]; // wave-uniform base
            __builtin_amdgcn_global_load_lds((const __attribute__((address_space(1))) void*)src,
                                             (__attribute__((address_space(3))) void*)dst, 16, 0, 0);
        }
    };

    // ---- A-side load state (tracked separately so prefetch can cross group boundaries) ----
    const char* lAbase = nullptr;
    int lrid0 = 0, lrid1 = 0, lisbf = 0;
    auto setGroup = [&](int g) {
        const void* Ag = (g == 0) ? A0 : ((g == 1) ? A1 : A2);
        const int* ig = (g == 0) ? idx0 : ((g == 1) ? idx1 : idx2);
        lisbf = (bfmask >> g) & 1;
        lrid0 = ig ? ig[r0] : r0;
        lrid1 = ig ? ig[r1] : r1;
        lAbase = (const char*)Ag;
    };

    float4 pf0, pf1, pf2, pf3;  // f32 prefetch regs (2 rows x 8 floats)
    bf16x8 pb0, pb1;            // bf16 prefetch regs
    int curbf = 0;              // dtype of data currently in prefetch regs

    auto issueA = [&](int st) {
        if ((st & 3) == 0) setGroup(st >> 2);
        curbf = lisbf;
        const size_t kel = (size_t)((st & 3) << 5) + (lk << 3);
        if (lisbf) {
            pb0 = *(const bf16x8*)(lAbase + (((size_t)lrid0 * HH + kel) << 1));
            pb1 = *(const bf16x8*)(lAbase + (((size_t)lrid1 * HH + kel) << 1));
        } else {
            const float* p0 = (const float*)lAbase + (size_t)lrid0 * HH + kel;
            const float* p1 = (const float*)lAbase + (size_t)lrid1 * HH + kel;
            pf0 = *(const float4*)p0; pf1 = *(const float4*)(p0 + 4);
            pf2 = *(const float4*)p1; pf3 = *(const float4*)(p1 + 4);
        }
    };

    stageB(0, 0);
    issueA(0);
    __syncthreads();

    int cur = 0;
    for (int st = 0; st < nt; ++st) {
        // consume prefetched A (loaded last step; latency absorbed by the barrier drain)
        bf16x8 a0, a1;
        if (curbf) { a0 = pb0; a1 = pb1; }
        else {
            a0 = (bf16x8){(short)f2bf(pf0.x), (short)f2bf(pf0.y), (short)f2bf(pf0.z), (short)f2bf(pf0.w),
                          (short)f2bf(pf1.x), (short)f2bf(pf1.y), (short)f2bf(pf1.z), (short)f2bf(pf1.w)};
            a1 = (bf16x8){(short)f2bf(pf2.x), (short)f2bf(pf2.y), (short)f2bf(pf2.z), (short)f2bf(pf2.w),
                          (short)f2bf(pf3.x), (short)f2bf(pf3.y), (short)f2bf(pf3.z), (short)f2bf(pf3.w)};
        }

        // issue next step's B staging and A gather before this step's MFMAs/barrier
        if (st + 1 < nt) { stageB(st + 1, cur ^ 1); issueA(st + 1); }

        const unsigned short* bs = &Bs[cur][colw << 12];
        bf16x8 b[8];
        #pragma unroll
        for (int nf = 0; nf < 8; ++nf) {
            int off = ((lr + (nf << 4)) << 5) + ((lk ^ (lr & 3)) << 3);
            b[nf] = *(const bf16x8*)(bs + off);
        }
        #pragma unroll
        for (int nf = 0; nf < 8; ++nf) {
            acc[0][nf] = __builtin_amdgcn_mfma_f32_16x16x32_bf16(a0, b[nf], acc[0][nf], 0, 0, 0);
            acc[1][nf] = __builtin_amdgcn_mfma_f32_16x16x32_bf16(a1, b[nf], acc[1][nf], 0, 0, 0);
        }
        __syncthreads();
        cur ^= 1;
    }

    // ---------------- epilogue ----------------
    float bias8[8];
    #pragma unroll
    for (int nf = 0; nf < 8; ++nf) bias8[nf] = bias[col0 + (nf << 4) + lr];

    if (mode == 3) {
        float g8[8], be8[8];
        #pragma unroll
        for (int nf = 0; nf < 8; ++nf) { g8[nf] = gamma[(nf << 4) + lr]; be8[nf] = beta[(nf << 4) + lr]; }
        #pragma unroll
        for (int mf = 0; mf < 2; ++mf) {
            #pragma unroll
            for (int rr = 0; rr < 4; ++rr) {
                int row = wrow + mf * 16 + lk * 4 + rr;
                bool ok = row < M;
                int rowc = ok ? row : M - 1;
                float x[8], sum = 0.f;
                #pragma unroll
                for (int nf = 0; nf < 8; ++nf) {
                    float v = fmaxf(acc[mf][nf][rr] + bias8[nf], 0.f);
                    v += resid[(size_t)rowc * HH + (nf << 4) + lr];
                    x[nf] = v; sum += v;
                }
                sum += __shfl_xor(sum, 1); sum += __shfl_xor(sum, 2);
                sum += __shfl_xor(sum, 4); sum += __shfl_xor(sum, 8);
                const float mean = sum * (1.f / 128.f);
                float vs = 0.f;
                #pragma unroll
                for (int nf = 0; nf < 8; ++nf) { float d = x[nf] - mean; vs += d * d; }
                vs += __shfl_xor(vs, 1); vs += __shfl_xor(vs, 2);
                vs += __shfl_xor(vs, 4); vs += __shfl_xor(vs, 8);
                const float rs = rsqrtf(vs * (1.f / 128.f) + 1e-5f);
                if (ok) {
                    #pragma unroll
                    for (int nf = 0; nf < 8; ++nf)
                        Cf[(size_t)row * out_ld + (nf << 4) + lr] = (x[nf] - mean) * rs * g8[nf] + be8[nf];
                }
            }
        }
    } else {
        #pragma unroll
        for (int mf = 0; mf < 2; ++mf) {
            #pragma unroll
            for (int rr = 0; rr < 4; ++rr) {
                int row = wrow + mf * 16 + lk * 4 + rr;
                if (row >= M) continue;
                #pragma unroll
                for (int nf = 0; nf < 8; ++nf) {
                    float v = acc[mf][nf][rr] + bias8[nf];
                    if (mode == 1 || mode == 4) v = fmaxf(v, 0.f);
                    size_t o = (size_t)row * out_ld + col0 + (nf << 4) + lr;
                    if (mode == 0 || mode == 1) Cf[o] = v;
                    else Cb[o] = f2bf(v);
                }
            }
        }
    }
}

// ---------------- attention scores: s[e,h] = <Q[dst[e],h,:], K[e,h,:]> / sqrt(32) ----------------
__global__ __launch_bounds__(256) void score_k(const float* __restrict__ Q,
                                               const __hip_bfloat16* __restrict__ KV,
                                               const int* __restrict__ dst,
                                               float* __restrict__ s)
{
    const int t = threadIdx.x;
    const int e = blockIdx.x * 2 + (t >> 7);
    const int c = t & 127;
    const int d = dst[e];
    const float q = Q[(size_t)d * HH + c];
    const float k = __bfloat162float(KV[(size_t)e * 256 + c]);
    float p = q * k;
    p += __shfl_xor(p, 16); p += __shfl_xor(p, 8);
    p += __shfl_xor(p, 4);  p += __shfl_xor(p, 2); p += __shfl_xor(p, 1);
    if ((t & 31) == 0) s[(size_t)e * 4 + (c >> 5)] = p * 0.17677669529663687f;
}

// ---------------- per-node online-softmax aggregation (one wave per node) ----------------
__global__ __launch_bounds__(256) void agg_k(const __hip_bfloat16* __restrict__ KV,
                                             const float* __restrict__ s,
                                             const int* __restrict__ offsets,
                                             const int* __restrict__ eids,
                                             float* __restrict__ hagg)
{
    const int t = threadIdx.x;
    const int n = blockIdx.x * 4 + (t >> 6);
    if (n >= NN) return;
    const int lane = t & 63;
    const int c0 = lane, c1 = lane + 64;
    const int h0 = lane >> 5, h1 = h0 + 2;
    const int o0 = offsets[n], o1 = offsets[n + 1];
    float m0 = -1e30f, m1 = -1e30f, d0 = 0.f, d1 = 0.f, a0 = 0.f, a1 = 0.f;
    for (int j = o0; j < o1; ++j) {
        const int e = eids[j];
        const float s0 = s[(size_t)e * 4 + h0];
        const float s1 = s[(size_t)e * 4 + h1];
        const float v0 = __bfloat162float(KV[(size_t)e * 256 + 128 + c0]);
        const float v1 = __bfloat162float(KV[(size_t)e * 256 + 128 + c1]);
        float nm = fmaxf(m0, s0);
        float sc = __expf(m0 - nm);
        float w  = __expf(s0 - nm);
        d0 = d0 * sc + w; a0 = a0 * sc + w * v0; m0 = nm;
        nm = fmaxf(m1, s1);
        sc = __expf(m1 - nm);
        w  = __expf(s1 - nm);
        d1 = d1 * sc + w; a1 = a1 * sc + w * v1; m1 = nm;
    }
    const bool any = (o1 > o0);
    hagg[(size_t)n * HH + c0] = any ? (a0 / d0) : 0.f;
    hagg[(size_t)n * HH + c1] = any ? (a1 / d1) : 0.f;
}

extern "C" void kernel_launch(void* const* d_in, const int* in_sizes, int n_in,
                              void* d_out, int out_size, void* d_ws, size_t ws_size,
                              hipStream_t stream)
{
    const float* h   = (const float*)d_in[0];
    const float* e   = (const float*)d_in[1];
    const int*   src = (const int*)d_in[2];
    const int*   dst = (const int*)d_in[3];
    const float* Wq  = (const float*)d_in[4];
    const float* bq  = (const float*)d_in[5];
    const float* Wk  = (const float*)d_in[6];
    const float* bk  = (const float*)d_in[7];
    const float* Wv  = (const float*)d_in[8];
    const float* bv  = (const float*)d_in[9];
    const float* Wn1 = (const float*)d_in[10];
    const float* bn1 = (const float*)d_in[11];
    const float* Wn2 = (const float*)d_in[12];
    const float* bn2 = (const float*)d_in[13];
    const float* We1 = (const float*)d_in[14];
    const float* be1 = (const float*)d_in[15];
    const float* We2 = (const float*)d_in[16];
    const float* be2 = (const float*)d_in[17];
    const float* gh  = (const float*)d_in[18];
    const float* bh  = (const float*)d_in[19];
    const float* ge  = (const float*)d_in[20];
    const float* be_ = (const float*)d_in[21];
    (void)in_sizes; (void)n_in; (void)out_size; (void)ws_size;

    float* h_out = (float*)d_out;
    float* e_out = (float*)d_out + (size_t)NN * HH;

    char* ws = (char*)d_ws;
    size_t off = 0;
    auto carve = [&](size_t bytes) { void* p = ws + off; off += (bytes + 255) & ~(size_t)255; return p; };
    __hip_bfloat16* KV = (__hip_bfloat16*)carve((size_t)EE * 256 * 2); // reused as t_edge (bf16 [E][128]) after agg
    unsigned short* t_edge = (unsigned short*)KV;
    float* Q      = (float*)carve((size_t)NN * HH * 4);
    float* sbuf   = (float*)carve((size_t)EE * 4 * 4);
    float* hagg   = (float*)carve((size_t)NN * HH * 4);
    float* tnode  = (float*)carve((size_t)NN * HH * 4);
    int* cursor   = (int*)carve((size_t)NN * 4);
    int* offsets  = (int*)carve((size_t)(NN + 1) * 4);
    int* bsum     = (int*)carve(256 * 4);
    int* eids     = (int*)carve((size_t)EE * 4);
    unsigned short* Wq_s  = (unsigned short*)carve(128 * 128 * 2);
    unsigned short* Wkv_s = (unsigned short*)carve(256 * 256 * 2);
    unsigned short* Wn1_s = (unsigned short*)carve(128 * 128 * 2);
    unsigned short* Wn2_s = (unsigned short*)carve(128 * 128 * 2);
    unsigned short* We1_s = (unsigned short*)carve(128 * 384 * 2);
    unsigned short* We2_s = (unsigned short*)carve(128 * 128 * 2);
    float* b_kv   = (float*)carve(256 * 4);

    const int nb = (NN + 255) / 256;

    // weight prep (bf16 transpose + chunk swizzle) + combined KV bias
    wprep_k<<<(128 * 128 + 255) / 256, 256, 0, stream>>>(Wq,  Wq_s,  128, 128, 0, 128);
    wprep_k<<<(256 * 128 + 255) / 256, 256, 0, stream>>>(Wk,  Wkv_s, 256, 128, 0, 256);
    wprep_k<<<(256 * 128 + 255) / 256, 256, 0, stream>>>(Wv,  Wkv_s, 256, 128, 128, 256);
    wprep_k<<<(128 * 128 + 255) / 256, 256, 0, stream>>>(Wn1, Wn1_s, 128, 128, 0, 128);
    wprep_k<<<(128 * 128 + 255) / 256, 256, 0, stream>>>(Wn2, Wn2_s, 128, 128, 0, 128);
    wprep_k<<<(384 * 128 + 255) / 256, 256, 0, stream>>>(We1, We1_s, 384, 128, 0, 384);
    wprep_k<<<(128 * 128 + 255) / 256, 256, 0, stream>>>(We2, We2_s, 128, 128, 0, 128);
    hipMemcpyAsync(b_kv,       bk, 128 * 4, hipMemcpyDeviceToDevice, stream);
    hipMemcpyAsync(b_kv + 128, bv, 128 * 4, hipMemcpyDeviceToDevice, stream);

    // CSR build
    hipMemsetAsync(cursor, 0, (size_t)NN * 4, stream);
    hist_k<<<(EE + 255) / 256, 256, 0, stream>>>(dst, cursor);
    blocksum_k<<<nb, 256, 0, stream>>>(cursor, bsum);
    scanb_k<<<1, 256, 0, stream>>>(bsum, nb);
    offsets_k<<<nb, 256, 0, stream>>>(cursor, bsum, offsets, cursor);
    fill_k<<<(EE + 255) / 256, 256, 0, stream>>>(dst, cursor, eids);

    // Q = h @ Wq + bq  (f32 out)
    mm_k<1><<<dim3((NN + 127) / 128, 1), 256, 0, stream>>>(
        h, nullptr, nullptr, nullptr, nullptr, nullptr, 0,
        Wq_s, bq, NN, 128, 0, Q, nullptr, 128, nullptr, nullptr, nullptr);

    // K|V = [h[src], e] @ [Wk|Wv] + [bk|bv]  (bf16 interleaved [E][256])
    // single pass over A: 8-wave blocks compute both 128-col halves -> e read once from HBM
    mm_k<2><<<dim3(EE / 128, 1), 512, 0, stream>>>(
        h, src, e, nullptr, nullptr, nullptr, 0,
        Wkv_s, b_kv, EE, 256, 2, nullptr, (unsigned short*)KV, 256, nullptr, nullptr, nullptr);

    score_k<<<EE / 2, 256, 0, stream>>>(Q, KV, dst, sbuf);
    agg_k<<<(NN + 3) / 4, 256, 0, stream>>>(KV, sbuf, offsets, eids, hagg);

    // node MLP + residual + LN -> h_out
    mm_k<1><<<dim3((NN + 127) / 128, 1), 256, 0, stream>>>(
        hagg, nullptr, nullptr, nullptr, nullptr, nullptr, 0,
        Wn1_s, bn1, NN, 128, 1, tnode, nullptr, 128, nullptr, nullptr, nullptr);
    mm_k<1><<<dim3((NN + 127) / 128, 1), 256, 0, stream>>>(
        tnode, nullptr, nullptr, nullptr, nullptr, nullptr, 0,
        Wn2_s, bn2, NN, 128, 3, h_out, nullptr, 128, h, gh, bh);

    // edge MLP on [h_out[src], h_out[dst], e] + residual + LN -> e_out
    mm_k<1><<<dim3(EE / 128, 1), 256, 0, stream>>>(
        h_out, src, h_out, dst, e, nullptr, 0,
        We1_s, be1, EE, 384, 4, nullptr, t_edge, 128, nullptr, nullptr, nullptr);
    mm_k<1><<<dim3(EE / 128, 1), 256, 0, stream>>>(
        t_edge, nullptr, nullptr, nullptr, nullptr, nullptr, 1,
        We2_s, be2, EE, 128, 3, e_out, nullptr, 128, e, ge, be_);
}

// Round 2
// 1656.885 us; speedup vs baseline: 1.0298x; 1.0174x over previous
//
#include <hip/hip_runtime.h>
#include <hip/hip_bf16.h>

#define NN 50000
#define EE 800000
#define HH 128

typedef __attribute__((ext_vector_type(8))) short bf16x8;
typedef __attribute__((ext_vector_type(4))) float f32x4;

__device__ inline unsigned short f2bf(float f) {
    union { float f; unsigned u; } v; v.f = f;
    unsigned r = v.u + 0x7FFF + ((v.u >> 16) & 1);
    return (unsigned short)(r >> 16);
}

// ---------------- CSR build (edges grouped by dst) ----------------
__global__ __launch_bounds__(256) void hist_k(const int* __restrict__ dst, int* __restrict__ cnt) {
    int i = blockIdx.x * 256 + threadIdx.x;
    if (i < EE) atomicAdd(&cnt[dst[i]], 1);
}

__global__ __launch_bounds__(256) void blocksum_k(const int* __restrict__ cnt, int* __restrict__ bsum) {
    __shared__ int sm[256];
    int i = blockIdx.x * 256 + threadIdx.x;
    sm[threadIdx.x] = (i < NN) ? cnt[i] : 0;
    __syncthreads();
    for (int s = 128; s > 0; s >>= 1) {
        if (threadIdx.x < s) sm[threadIdx.x] += sm[threadIdx.x + s];
        __syncthreads();
    }
    if (threadIdx.x == 0) bsum[blockIdx.x] = sm[0];
}

__global__ __launch_bounds__(256) void scanb_k(int* __restrict__ bsum, int nb) {
    __shared__ int sm[256];
    int t = threadIdx.x;
    sm[t] = (t < nb) ? bsum[t] : 0;
    __syncthreads();
    for (int d = 1; d < 256; d <<= 1) {
        int v = (t >= d) ? sm[t - d] : 0;
        __syncthreads();
        sm[t] += v;
        __syncthreads();
    }
    if (t < nb) bsum[t] = sm[t];
}

__global__ __launch_bounds__(256) void offsets_k(const int* __restrict__ cnt, const int* __restrict__ bsum,
                                                 int* __restrict__ offsets, int* __restrict__ cursor) {
    __shared__ int sm[256];
    int b = blockIdx.x, t = threadIdx.x;
    int i = b * 256 + t;
    int c = (i < NN) ? cnt[i] : 0;
    sm[t] = c;
    __syncthreads();
    for (int d = 1; d < 256; d <<= 1) {
        int v = (t >= d) ? sm[t - d] : 0;
        __syncthreads();
        sm[t] += v;
        __syncthreads();
    }
    int incl = sm[t];
    int base = (b == 0) ? 0 : bsum[b - 1];
    int off = base + incl - c;
    if (i < NN) { offsets[i] = off; cursor[i] = off; }
    if (i == NN - 1) offsets[NN] = off + c;
}

__global__ __launch_bounds__(256) void fill_k(const int* __restrict__ dst, int* __restrict__ cursor,
                                              int* __restrict__ eids) {
    int i = blockIdx.x * 256 + threadIdx.x;
    if (i < EE) { int p = atomicAdd(&cursor[dst[i]], 1); eids[p] = i; }
}

// ---------------- weight prep: W[fi][fo] f32 -> W''[n][k] bf16, chunk-swizzled ----------------
// W''_swz[n][kb*32 + c*8 + j] = W[kb*32 + (c^(n&3))*8 + j][n]
// so a LINEAR global_load_lds into LDS[n][c] lands orig chunk (c^(n&3)); reader XORs.
__global__ __launch_bounds__(256) void wprep_k(const float* __restrict__ W, unsigned short* __restrict__ out,
                                               int fi, int fo, int n_off, int out_ld) {
    int i = blockIdx.x * 256 + threadIdx.x;
    if (i >= fi * fo) return;
    int n = i / fi, kout = i - n * fi;
    int c = (kout >> 3) & 3;
    int ksrc = (kout & ~31) | (((c ^ (n & 3)) & 3) << 3) | (kout & 7);
    out[(size_t)(n_off + n) * out_ld + kout] = f2bf(W[(size_t)ksrc * fo + n]);
}

// ---------------- MFMA gather-GEMM ----------------
// C[M, CW*128 per block] = act( concat_g Ag[idx_g(row)] @ W + bias )
// 4 waves / 256 threads. Per-wave tile 16x128 (M_rep=1, N_rep=8 of 16x16x32 bf16 MFMA).
//   -> acc = 32 AGPR (vs 64 before): total regs < 128 -> 4 waves/SIMD -> 4 blocks/CU
//      (the old 32x128 wave tile pinned occupancy at 2 waves/SIMD: 68 VGPR + 64 AGPR = 132).
// CW=1: block 64x128 (4 row-waves). CW=2: block 32x256 (2 row x 2 col waves; both col
//   halves share the A stream so e is read from HBM once).
// A: direct global loads (f32->bf16 inline, or bf16 passthrough per bfmask bit),
//    software-pipelined one k-step ahead.
// W: bf16 [NCtot][Ktot] pre-swizzled; staged to LDS via global_load_lds, double-buffered.
// mode: 0 f32, 1 f32+relu, 2 bf16, 4 bf16+relu, 3 relu+resid+LayerNorm(128) f32.
template <int CW>
__global__ __launch_bounds__(256, 4) void mm_k(
    const void* __restrict__ A0, const int* __restrict__ idx0,
    const void* __restrict__ A1, const int* __restrict__ idx1,
    const void* __restrict__ A2, const int* __restrict__ idx2,
    int bfmask,
    const unsigned short* __restrict__ Wsz, const float* __restrict__ bias,
    int M, int Ktot, int mode,
    float* __restrict__ Cf, unsigned short* __restrict__ Cb, int out_ld,
    const float* __restrict__ resid, const float* __restrict__ gamma, const float* __restrict__ beta)
{
    __shared__ unsigned short Bs[2][CW * 4096]; // 2 x (CW*8KB): [n(CW*128)][k(32)] bf16, chunk-swizzled
    const int t = threadIdx.x;
    const int wid = t >> 6, lane = t & 63;
    const int colw = (CW == 1) ? 0 : (wid & (CW - 1)); // col-wave
    const int roww = wid / CW;                          // row-wave
    const int RW = 4 / CW;
    const int lr = lane & 15, lk = lane >> 4;
    const int ncb = blockIdx.y * (CW << 7);   // first output col of this block
    const int col0 = ncb + (colw << 7);       // first output col of this wave
    const int wrow = blockIdx.x * (RW << 4) + roww * 16;

    int r0 = wrow + lr; if (r0 >= M) r0 = M - 1;

    const int nt = Ktot >> 5;

    f32x4 acc[8];
    #pragma unroll
    for (int j = 0; j < 8; ++j) acc[j] = (f32x4){0.f, 0.f, 0.f, 0.f};

    // stage B k-block st into buffer buf (2*CW rounds of 256 lanes x 16B)
    auto stageB = [&](int st, int buf) {
        #pragma unroll
        for (int i = 0; i < 2 * CW; ++i) {
            int s = i * 256 + t;                                  // [0, CW*512)
            const unsigned short* src = Wsz + (size_t)(ncb + (s >> 2)) * Ktot + (st << 5) + ((s & 3) << 3);
            unsigned short* dst = &Bs[buf][(i << 11) + (wid << 9)]; // wave-uniform base
            __builtin_amdgcn_global_load_lds((const __attribute__((address_space(1))) void*)src,
                                             (__attribute__((address_space(3))) void*)dst, 16, 0, 0);
        }
    };

    // ---- A-side load state (tracked separately so prefetch can cross group boundaries) ----
    const char* lAbase = nullptr;
    int lrid0 = 0, lisbf = 0;
    auto setGroup = [&](int g) {
        const void* Ag = (g == 0) ? A0 : ((g == 1) ? A1 : A2);
        const int* ig = (g == 0) ? idx0 : ((g == 1) ? idx1 : idx2);
        lisbf = (bfmask >> g) & 1;
        lrid0 = ig ? ig[r0] : r0;
        lAbase = (const char*)Ag;
    };

    float4 pf0, pf1;   // f32 prefetch regs (1 row x 8 floats)
    bf16x8 pb0;        // bf16 prefetch reg
    int curbf = 0;     // dtype of data currently in prefetch regs

    auto issueA = [&](int st) {
        if ((st & 3) == 0) setGroup(st >> 2);
        curbf = lisbf;
        const size_t kel = (size_t)((st & 3) << 5) + (lk << 3);
        if (lisbf) {
            pb0 = *(const bf16x8*)(lAbase + (((size_t)lrid0 * HH + kel) << 1));
        } else {
            const float* p0 = (const float*)lAbase + (size_t)lrid0 * HH + kel;
            pf0 = *(const float4*)p0; pf1 = *(const float4*)(p0 + 4);
        }
    };

    stageB(0, 0);
    issueA(0);
    __syncthreads();

    int cur = 0;
    for (int st = 0; st < nt; ++st) {
        // consume prefetched A (loaded last step; latency absorbed by the barrier drain)
        bf16x8 a0;
        if (curbf) a0 = pb0;
        else a0 = (bf16x8){(short)f2bf(pf0.x), (short)f2bf(pf0.y), (short)f2bf(pf0.z), (short)f2bf(pf0.w),
                           (short)f2bf(pf1.x), (short)f2bf(pf1.y), (short)f2bf(pf1.z), (short)f2bf(pf1.w)};

        // issue next step's B staging and A gather before this step's MFMAs/barrier
        if (st + 1 < nt) { stageB(st + 1, cur ^ 1); issueA(st + 1); }

        const unsigned short* bs = &Bs[cur][colw << 12];
        bf16x8 b[8];
        #pragma unroll
        for (int nf = 0; nf < 8; ++nf) {
            int off = ((lr + (nf << 4)) << 5) + ((lk ^ (lr & 3)) << 3);
            b[nf] = *(const bf16x8*)(bs + off);
        }
        #pragma unroll
        for (int nf = 0; nf < 8; ++nf)
            acc[nf] = __builtin_amdgcn_mfma_f32_16x16x32_bf16(a0, b[nf], acc[nf], 0, 0, 0);
        __syncthreads();
        cur ^= 1;
    }

    // ---------------- epilogue ----------------
    float bias8[8];
    #pragma unroll
    for (int nf = 0; nf < 8; ++nf) bias8[nf] = bias[col0 + (nf << 4) + lr];

    if (mode == 3) {
        float g8[8], be8[8];
        #pragma unroll
        for (int nf = 0; nf < 8; ++nf) { g8[nf] = gamma[(nf << 4) + lr]; be8[nf] = beta[(nf << 4) + lr]; }
        #pragma unroll
        for (int rr = 0; rr < 4; ++rr) {
            int row = wrow + lk * 4 + rr;
            bool ok = row < M;
            int rowc = ok ? row : M - 1;
            float x[8], sum = 0.f;
            #pragma unroll
            for (int nf = 0; nf < 8; ++nf) {
                float v = fmaxf(acc[nf][rr] + bias8[nf], 0.f);
                v += resid[(size_t)rowc * HH + (nf << 4) + lr];
                x[nf] = v; sum += v;
            }
            sum += __shfl_xor(sum, 1); sum += __shfl_xor(sum, 2);
            sum += __shfl_xor(sum, 4); sum += __shfl_xor(sum, 8);
            const float mean = sum * (1.f / 128.f);
            float vs = 0.f;
            #pragma unroll
            for (int nf = 0; nf < 8; ++nf) { float d = x[nf] - mean; vs += d * d; }
            vs += __shfl_xor(vs, 1); vs += __shfl_xor(vs, 2);
            vs += __shfl_xor(vs, 4); vs += __shfl_xor(vs, 8);
            const float rs = rsqrtf(vs * (1.f / 128.f) + 1e-5f);
            if (ok) {
                #pragma unroll
                for (int nf = 0; nf < 8; ++nf)
                    Cf[(size_t)row * out_ld + (nf << 4) + lr] = (x[nf] - mean) * rs * g8[nf] + be8[nf];
            }
        }
    } else {
        #pragma unroll
        for (int rr = 0; rr < 4; ++rr) {
            int row = wrow + lk * 4 + rr;
            if (row >= M) continue;
            #pragma unroll
            for (int nf = 0; nf < 8; ++nf) {
                float v = acc[nf][rr] + bias8[nf];
                if (mode == 1 || mode == 4) v = fmaxf(v, 0.f);
                size_t o = (size_t)row * out_ld + col0 + (nf << 4) + lr;
                if (mode == 0 || mode == 1) Cf[o] = v;
                else Cb[o] = f2bf(v);
            }
        }
    }
}

// ---------------- attention scores: s[e,h] = <Q[dst[e],h,:], K[e,h,:]> / sqrt(32) ----------------
__global__ __launch_bounds__(256) void score_k(const float* __restrict__ Q,
                                               const __hip_bfloat16* __restrict__ KV,
                                               const int* __restrict__ dst,
                                               float* __restrict__ s)
{
    const int t = threadIdx.x;
    const int e = blockIdx.x * 2 + (t >> 7);
    const int c = t & 127;
    const int d = dst[e];
    const float q = Q[(size_t)d * HH + c];
    const float k = __bfloat162float(KV[(size_t)e * 256 + c]);
    float p = q * k;
    p += __shfl_xor(p, 16); p += __shfl_xor(p, 8);
    p += __shfl_xor(p, 4);  p += __shfl_xor(p, 2); p += __shfl_xor(p, 1);
    if ((t & 31) == 0) s[(size_t)e * 4 + (c >> 5)] = p * 0.17677669529663687f;
}

// ---------------- per-node online-softmax aggregation (one wave per node) ----------------
__global__ __launch_bounds__(256) void agg_k(const __hip_bfloat16* __restrict__ KV,
                                             const float* __restrict__ s,
                                             const int* __restrict__ offsets,
                                             const int* __restrict__ eids,
                                             float* __restrict__ hagg)
{
    const int t = threadIdx.x;
    const int n = blockIdx.x * 4 + (t >> 6);
    if (n >= NN) return;
    const int lane = t & 63;
    const int c0 = lane, c1 = lane + 64;
    const int h0 = lane >> 5, h1 = h0 + 2;
    const int o0 = offsets[n], o1 = offsets[n + 1];
    float m0 = -1e30f, m1 = -1e30f, d0 = 0.f, d1 = 0.f, a0 = 0.f, a1 = 0.f;
    for (int j = o0; j < o1; ++j) {
        const int e = eids[j];
        const float s0 = s[(size_t)e * 4 + h0];
        const float s1 = s[(size_t)e * 4 + h1];
        const float v0 = __bfloat162float(KV[(size_t)e * 256 + 128 + c0]);
        const float v1 = __bfloat162float(KV[(size_t)e * 256 + 128 + c1]);
        float nm = fmaxf(m0, s0);
        float sc = __expf(m0 - nm);
        float w  = __expf(s0 - nm);
        d0 = d0 * sc + w; a0 = a0 * sc + w * v0; m0 = nm;
        nm = fmaxf(m1, s1);
        sc = __expf(m1 - nm);
        w  = __expf(s1 - nm);
        d1 = d1 * sc + w; a1 = a1 * sc + w * v1; m1 = nm;
    }
    const bool any = (o1 > o0);
    hagg[(size_t)n * HH + c0] = any ? (a0 / d0) : 0.f;
    hagg[(size_t)n * HH + c1] = any ? (a1 / d1) : 0.f;
}

extern "C" void kernel_launch(void* const* d_in, const int* in_sizes, int n_in,
                              void* d_out, int out_size, void* d_ws, size_t ws_size,
                              hipStream_t stream)
{
    const float* h   = (const float*)d_in[0];
    const float* e   = (const float*)d_in[1];
    const int*   src = (const int*)d_in[2];
    const int*   dst = (const int*)d_in[3];
    const float* Wq  = (const float*)d_in[4];
    const float* bq  = (const float*)d_in[5];
    const float* Wk  = (const float*)d_in[6];
    const float* bk  = (const float*)d_in[7];
    const float* Wv  = (const float*)d_in[8];
    const float* bv  = (const float*)d_in[9];
    const float* Wn1 = (const float*)d_in[10];
    const float* bn1 = (const float*)d_in[11];
    const float* Wn2 = (const float*)d_in[12];
    const float* bn2 = (const float*)d_in[13];
    const float* We1 = (const float*)d_in[14];
    const float* be1 = (const float*)d_in[15];
    const float* We2 = (const float*)d_in[16];
    const float* be2 = (const float*)d_in[17];
    const float* gh  = (const float*)d_in[18];
    const float* bh  = (const float*)d_in[19];
    const float* ge  = (const float*)d_in[20];
    const float* be_ = (const float*)d_in[21];
    (void)in_sizes; (void)n_in; (void)out_size; (void)ws_size;

    float* h_out = (float*)d_out;
    float* e_out = (float*)d_out + (size_t)NN * HH;

    char* ws = (char*)d_ws;
    size_t off = 0;
    auto carve = [&](size_t bytes) { void* p = ws + off; off += (bytes + 255) & ~(size_t)255; return p; };
    __hip_bfloat16* KV = (__hip_bfloat16*)carve((size_t)EE * 256 * 2); // reused as t_edge (bf16 [E][128]) after agg
    unsigned short* t_edge = (unsigned short*)KV;
    float* Q      = (float*)carve((size_t)NN * HH * 4);
    float* sbuf   = (float*)carve((size_t)EE * 4 * 4);
    float* hagg   = (float*)carve((size_t)NN * HH * 4);
    float* tnode  = (float*)carve((size_t)NN * HH * 4);
    int* cursor   = (int*)carve((size_t)NN * 4);
    int* offsets  = (int*)carve((size_t)(NN + 1) * 4);
    int* bsum     = (int*)carve(256 * 4);
    int* eids     = (int*)carve((size_t)EE * 4);
    unsigned short* Wq_s  = (unsigned short*)carve(128 * 128 * 2);
    unsigned short* Wkv_s = (unsigned short*)carve(256 * 256 * 2);
    unsigned short* Wn1_s = (unsigned short*)carve(128 * 128 * 2);
    unsigned short* Wn2_s = (unsigned short*)carve(128 * 128 * 2);
    unsigned short* We1_s = (unsigned short*)carve(128 * 384 * 2);
    unsigned short* We2_s = (unsigned short*)carve(128 * 128 * 2);
    float* b_kv   = (float*)carve(256 * 4);

    const int nb = (NN + 255) / 256;

    // weight prep (bf16 transpose + chunk swizzle) + combined KV bias
    wprep_k<<<(128 * 128 + 255) / 256, 256, 0, stream>>>(Wq,  Wq_s,  128, 128, 0, 128);
    wprep_k<<<(256 * 128 + 255) / 256, 256, 0, stream>>>(Wk,  Wkv_s, 256, 128, 0, 256);
    wprep_k<<<(256 * 128 + 255) / 256, 256, 0, stream>>>(Wv,  Wkv_s, 256, 128, 128, 256);
    wprep_k<<<(128 * 128 + 255) / 256, 256, 0, stream>>>(Wn1, Wn1_s, 128, 128, 0, 128);
    wprep_k<<<(128 * 128 + 255) / 256, 256, 0, stream>>>(Wn2, Wn2_s, 128, 128, 0, 128);
    wprep_k<<<(384 * 128 + 255) / 256, 256, 0, stream>>>(We1, We1_s, 384, 128, 0, 384);
    wprep_k<<<(128 * 128 + 255) / 256, 256, 0, stream>>>(We2, We2_s, 128, 128, 0, 128);
    hipMemcpyAsync(b_kv,       bk, 128 * 4, hipMemcpyDeviceToDevice, stream);
    hipMemcpyAsync(b_kv + 128, bv, 128 * 4, hipMemcpyDeviceToDevice, stream);

    // CSR build
    hipMemsetAsync(cursor, 0, (size_t)NN * 4, stream);
    hist_k<<<(EE + 255) / 256, 256, 0, stream>>>(dst, cursor);
    blocksum_k<<<nb, 256, 0, stream>>>(cursor, bsum);
    scanb_k<<<1, 256, 0, stream>>>(bsum, nb);
    offsets_k<<<nb, 256, 0, stream>>>(cursor, bsum, offsets, cursor);
    fill_k<<<(EE + 255) / 256, 256, 0, stream>>>(dst, cursor, eids);

    // Q = h @ Wq + bq  (f32 out)  [64 rows/block]
    mm_k<1><<<dim3((NN + 63) / 64, 1), 256, 0, stream>>>(
        h, nullptr, nullptr, nullptr, nullptr, nullptr, 0,
        Wq_s, bq, NN, 128, 0, Q, nullptr, 128, nullptr, nullptr, nullptr);

    // K|V = [h[src], e] @ [Wk|Wv] + [bk|bv]  (bf16 interleaved [E][256])
    // CW=2: 32x256 tile, both col halves share the A stream -> e read once from HBM
    mm_k<2><<<dim3(EE / 32, 1), 256, 0, stream>>>(
        h, src, e, nullptr, nullptr, nullptr, 0,
        Wkv_s, b_kv, EE, 256, 2, nullptr, (unsigned short*)KV, 256, nullptr, nullptr, nullptr);

    score_k<<<EE / 2, 256, 0, stream>>>(Q, KV, dst, sbuf);
    agg_k<<<(NN + 3) / 4, 256, 0, stream>>>(KV, sbuf, offsets, eids, hagg);

    // node MLP + residual + LN -> h_out
    mm_k<1><<<dim3((NN + 63) / 64, 1), 256, 0, stream>>>(
        hagg, nullptr, nullptr, nullptr, nullptr, nullptr, 0,
        Wn1_s, bn1, NN, 128, 1, tnode, nullptr, 128, nullptr, nullptr, nullptr);
    mm_k<1><<<dim3((NN + 63) / 64, 1), 256, 0, stream>>>(
        tnode, nullptr, nullptr, nullptr, nullptr, nullptr, 0,
        Wn2_s, bn2, NN, 128, 3, h_out, nullptr, 128, h, gh, bh);

    // edge MLP on [h_out[src], h_out[dst], e] + residual + LN -> e_out
    mm_k<1><<<dim3(EE / 64, 1), 256, 0, stream>>>(
        h_out, src, h_out, dst, e, nullptr, 0,
        We1_s, be1, EE, 384, 4, nullptr, t_edge, 128, nullptr, nullptr, nullptr);
    mm_k<1><<<dim3(EE / 64, 1), 256, 0, stream>>>(
        t_edge, nullptr, nullptr, nullptr, nullptr, nullptr, 1,
        We2_s, be2, EE, 128, 3, e_out, nullptr, 128, e, ge, be_);
}